// Round 4
// baseline (467.105 us; speedup 1.0000x reference)
//
#include <hip/hip_runtime.h>
#include <math.h>

typedef float    f4 __attribute__((ext_vector_type(4)));
typedef _Float16 h8 __attribute__((ext_vector_type(8)));
typedef _Float16 h4 __attribute__((ext_vector_type(4)));

static constexpr int cBS = 8, cB = 4, cM = 256, cD = 256, cN = 2048;
static constexpr size_t KV_ELEMS = (size_t)cBS * cB * cM * cD;      // 2,097,152 floats
static constexpr size_t KV_BYTES_F16 = 2 * KV_ELEMS * 2;            // Kh + VTh = 8 MB
static constexpr size_t YPART_ELEMS = (size_t)cBS * cB * cN * cD;   // 16,777,216 floats
static constexpr size_t YPART_BYTES = YPART_ELEMS * 4;              // 64 MB

// select v[c>>2][c&3] with compile-time indices only (avoid scratch)
__device__ __forceinline__ float sel16(const float v[4][4], int c) {
  float s = v[0][0];
#pragma unroll
  for (int a = 0; a < 4; ++a)
#pragma unroll
    for (int r = 0; r < 4; ++r) {
      int idx = a * 4 + r;
      if (idx) s = (c == idx) ? v[a][r] : s;
    }
  return s;
}

// out = -4 * seed  (atomic-fallback path only)
__global__ void k_init(const f4* __restrict__ seed, f4* __restrict__ out) {
  int i = blockIdx.x * 256 + threadIdx.x; // ×4 iters = 1,048,576 f4 = seed size
#pragma unroll
  for (int j = 0; j < 4; ++j) {
    int idx = i + j * 262144;
    f4 v = seed[idx];
    out[idx] = -4.0f * v;
  }
}

// out = ypart[k=0..3] summed - 4*seed   (ws path)
__global__ void k_reduce(const f4* __restrict__ seed, const f4* __restrict__ ypart,
                         f4* __restrict__ out) {
  int i = blockIdx.x * 256 + threadIdx.x;
#pragma unroll
  for (int j = 0; j < 4; ++j) {
    int idx = i + j * 262144;          // f4 index into out/seed
    int d4 = idx & 63;                 // d/4
    int n = (idx >> 6) & 2047;
    int b = idx >> 17;
    int nt = n >> 6, row = n & 63;
    size_t base = ((size_t)((b * 128 + nt) * 64 + row)) * 64 + d4; // k=0 tile
    f4 acc = ypart[base] + ypart[base + 131072] + ypart[base + 2 * 131072] +
             ypart[base + 3 * 131072];
    out[idx] = acc - 4.0f * seed[idx];
  }
}

// blocks [0,512): transpose V -> VT (f16, [bk][d][m]); blocks [512,1536): K -> f16
__global__ __launch_bounds__(256) void k_prep(const f4* __restrict__ K,
                                              unsigned short* __restrict__ Kh,
                                              const float* __restrict__ V,
                                              unsigned short* __restrict__ VT) {
  __shared__ float t[64][65];
  int bid = blockIdx.x;
  int tid = threadIdx.x;
  if (bid < 512) {
    int dt = bid & 3, mt = (bid >> 2) & 3, bkk = bid >> 4; // bkk 0..31
    const float* src = V + (size_t)bkk * 65536 + (size_t)(mt * 64) * 256 + dt * 64;
#pragma unroll
    for (int i = 0; i < 4; ++i) {
      int idx = tid + i * 256;
      int r = idx >> 4, cq = idx & 15;
      f4 v = *(const f4*)(src + (size_t)r * 256 + cq * 4);
      t[r][cq * 4 + 0] = v[0]; t[r][cq * 4 + 1] = v[1];
      t[r][cq * 4 + 2] = v[2]; t[r][cq * 4 + 3] = v[3];
    }
    __syncthreads();
    _Float16* dst = reinterpret_cast<_Float16*>(VT) + (size_t)bkk * 65536 +
                    (size_t)(dt * 64) * 256 + mt * 64;
#pragma unroll
    for (int i = 0; i < 4; ++i) {
      int idx = tid + i * 256;
      int d = idx >> 4, mq = idx & 15;
      h4 h;
      h[0] = (_Float16)t[mq * 4 + 0][d];
      h[1] = (_Float16)t[mq * 4 + 1][d];
      h[2] = (_Float16)t[mq * 4 + 2][d];
      h[3] = (_Float16)t[mq * 4 + 3][d];
      *(h4*)(dst + (size_t)d * 256 + mq * 4) = h;
    }
  } else {
    int i = (bid - 512) * 256 + tid; // ×2 iters = 524,288 f4 = K size
    _Float16* kp = reinterpret_cast<_Float16*>(Kh);
#pragma unroll
    for (int j = 0; j < 2; ++j) {
      int idx = i + j * 262144;
      f4 v = K[idx];
      h4 h;
      h[0] = (_Float16)v[0]; h[1] = (_Float16)v[1];
      h[2] = (_Float16)v[2]; h[3] = (_Float16)v[3];
      *(h4*)(kp + (size_t)idx * 4) = h;
    }
  }
}

template <bool PRE, bool PART>
__global__ __launch_bounds__(256)
__attribute__((amdgpu_waves_per_eu(2, 2)))  // VGPR cap 256: kernel needs ~200 live; the
                                            // r3 (256,2) hint made the allocator pick 128
                                            // and spill ~1 GB/dispatch to scratch.
void ep_main(const float* __restrict__ seed, const float* __restrict__ emK,
             const float* __restrict__ emV, const float* __restrict__ emS,
             const float* __restrict__ galpha, const float* __restrict__ gbias,
             const float* __restrict__ rtau, const unsigned short* __restrict__ KhRaw,
             const unsigned short* __restrict__ VThRaw, float* __restrict__ outOrPart) {
  __shared__ _Float16 stage[64 * 256]; // 32KB, swizzled; reused y-stage then P
  __shared__ float redmax[256], redsum[256], reddot[256];

  const int tid = threadIdx.x, wid = tid >> 6, lane = tid & 63;
  const int g = lane >> 4, c = lane & 15;
  const int bid = blockIdx.x;
  const int nt = bid & 31, k = (bid >> 5) & 3, b = bid >> 7;
  const int n0 = nt * 64, wm0 = wid * 64, wd0 = wid * 64;

  const float LOG2E = 1.4426950408889634f;
  float rt = rtau[k];
  float tau = ((rt > 20.f) ? rt : log1pf(expf(rt))) + 0.1f;
  float scale2 = LOG2E / tau;
  float ga = galpha[k] * (1.0f / 256.0f);
  float gb = gbias[k];

  float msk[4];
#pragma unroll
  for (int mh = 0; mh < 4; ++mh) {
    float sv = emS[(b * cB + k) * cM + wm0 + mh * 16 + c];
    msk[mh] = (sv > 0.f) ? 0.f : -1e30f;
  }

  // y state in C-layout: y[a][dh][r] = y[n0+a*16+g*4+r][wd0+dh*16+c]
  float y[4][4][4];
  {
    const float* s0 = seed + (size_t)b * cN * cD;
#pragma unroll
    for (int a = 0; a < 4; ++a)
#pragma unroll
      for (int r = 0; r < 4; ++r) {
        const float* rp = s0 + (size_t)(n0 + a * 16 + g * 4 + r) * cD + wd0 + c;
#pragma unroll
        for (int dh = 0; dh < 4; ++dh) y[a][dh][r] = rp[dh * 16];
      }
  }

  const size_t bk = (size_t)(b * cB + k);
  const _Float16* Kp = reinterpret_cast<const _Float16*>(KhRaw) + bk * cM * cD;
  const _Float16* VTp = reinterpret_cast<const _Float16*>(VThRaw) + bk * cD * cM;
  const float* Kf = emK + bk * cM * cD;
  const float* Vf = emV + bk * cM * cD;

  f4 acc[4][4];
  float rmax[4][4], rsum[4][4];

  for (int step = 0; step < 2; ++step) {
    // ---- stage y as f16 (swizzled) ----
#pragma unroll
    for (int a = 0; a < 4; ++a)
#pragma unroll
      for (int r = 0; r < 4; ++r) {
        int row = a * 16 + g * 4 + r;
        int sw = (row & 7) << 4;
#pragma unroll
        for (int dh = 0; dh < 4; ++dh) {
          int byte = ((row << 9) + ((wd0 + dh * 16 + c) << 1)) ^ sw;
          *(_Float16*)((char*)stage + byte) = (_Float16)y[a][dh][r];
        }
      }
    __syncthreads();

    // ---- S = y @ K^T (wave owns m-chunk wm0..wm0+63) ----
#pragma unroll
    for (int a = 0; a < 4; ++a)
#pragma unroll
      for (int mh = 0; mh < 4; ++mh)
#pragma unroll
        for (int r = 0; r < 4; ++r) acc[a][mh][r] = 0.f;

    for (int kk = 0; kk < 8; ++kk) {
      h8 A[4], Bv[4];
#pragma unroll
      for (int a = 0; a < 4; ++a) {
        int row = a * 16 + c;
        int byte = ((row << 9) + (kk << 6) + (g << 4)) ^ ((row & 7) << 4);
        A[a] = *(const h8*)((const char*)stage + byte);
      }
      if (PRE) {
#pragma unroll
        for (int mh = 0; mh < 4; ++mh)
          Bv[mh] = *(const h8*)(Kp + (size_t)(wm0 + mh * 16 + c) * cD + kk * 32 + g * 8);
      } else {
#pragma unroll
        for (int mh = 0; mh < 4; ++mh) {
          const float* p = Kf + (size_t)(wm0 + mh * 16 + c) * cD + kk * 32 + g * 8;
#pragma unroll
          for (int j = 0; j < 8; ++j) Bv[mh][j] = (_Float16)p[j];
        }
      }
#pragma unroll
      for (int a = 0; a < 4; ++a)
#pragma unroll
        for (int mh = 0; mh < 4; ++mh)
          acc[a][mh] = __builtin_amdgcn_mfma_f32_16x16x32_f16(A[a], Bv[mh], acc[a][mh], 0, 0, 0);
    }

    // ---- scale + mask + wave row-max ----
#pragma unroll
    for (int a = 0; a < 4; ++a)
#pragma unroll
      for (int r = 0; r < 4; ++r) {
#pragma unroll
        for (int mh = 0; mh < 4; ++mh)
          acc[a][mh][r] = fmaf(acc[a][mh][r], scale2, msk[mh]);
        float v = fmaxf(fmaxf(acc[a][0][r], acc[a][1][r]), fmaxf(acc[a][2][r], acc[a][3][r]));
        v = fmaxf(v, __shfl_xor(v, 1, 64));
        v = fmaxf(v, __shfl_xor(v, 2, 64));
        v = fmaxf(v, __shfl_xor(v, 4, 64));
        v = fmaxf(v, __shfl_xor(v, 8, 64));
        rmax[a][r] = v;
      }
    {
      int row = (c >> 2) * 16 + g * 4 + (c & 3);
      redmax[row * 4 + wid] = sel16(rmax, c);
    }
    __syncthreads();
#pragma unroll
    for (int a = 0; a < 4; ++a)
#pragma unroll
      for (int r = 0; r < 4; ++r) {
        f4 q = *(const f4*)&redmax[(a * 16 + g * 4 + r) * 4];
        rmax[a][r] = fmaxf(fmaxf(q[0], q[1]), fmaxf(q[2], q[3]));
      }

    // ---- exp ----
#pragma unroll
    for (int a = 0; a < 4; ++a)
#pragma unroll
      for (int mh = 0; mh < 4; ++mh)
#pragma unroll
        for (int r = 0; r < 4; ++r)
          acc[a][mh][r] = exp2f(acc[a][mh][r] - rmax[a][r]);

    // ---- write P (f16) into stage (safe: all y A-reads done before redmax barrier) ----
#pragma unroll
    for (int a = 0; a < 4; ++a)
#pragma unroll
      for (int r = 0; r < 4; ++r) {
        int row = a * 16 + g * 4 + r;
        int sw = (row & 7) << 4;
#pragma unroll
        for (int mh = 0; mh < 4; ++mh) {
          int byte = ((row << 9) + ((wm0 + mh * 16 + c) << 1)) ^ sw;
          *(_Float16*)((char*)stage + byte) = (_Float16)acc[a][mh][r];
        }
      }

    // ---- wave row-sum ----
#pragma unroll
    for (int a = 0; a < 4; ++a)
#pragma unroll
      for (int r = 0; r < 4; ++r) {
        float v = (acc[a][0][r] + acc[a][1][r]) + (acc[a][2][r] + acc[a][3][r]);
        v += __shfl_xor(v, 1, 64);
        v += __shfl_xor(v, 2, 64);
        v += __shfl_xor(v, 4, 64);
        v += __shfl_xor(v, 8, 64);
        rsum[a][r] = v;
      }
    {
      int row = (c >> 2) * 16 + g * 4 + (c & 3);
      redsum[row * 4 + wid] = sel16(rsum, c);
    }
    __syncthreads(); // also covers P-writes
#pragma unroll
    for (int a = 0; a < 4; ++a)
#pragma unroll
      for (int r = 0; r < 4; ++r) {
        f4 q = *(const f4*)&redsum[(a * 16 + g * 4 + r) * 4];
        float s = (q[0] + q[1]) + (q[2] + q[3]);
        rsum[a][r] = (s > 0.f && rmax[a][r] > -1e29f) ? (1.f / s) : 0.f;
      }

    // ---- delta = P @ V (wave owns d-chunk wd0..wd0+63) ----
#pragma unroll
    for (int a = 0; a < 4; ++a)
#pragma unroll
      for (int dh = 0; dh < 4; ++dh)
#pragma unroll
        for (int r = 0; r < 4; ++r) acc[a][dh][r] = 0.f;

    for (int kk = 0; kk < 8; ++kk) {
      h8 A[4], Bv[4];
#pragma unroll
      for (int a = 0; a < 4; ++a) {
        int row = a * 16 + c;
        int byte = ((row << 9) + (kk << 6) + (g << 4)) ^ ((row & 7) << 4);
        A[a] = *(const h8*)((const char*)stage + byte);
      }
      if (PRE) {
#pragma unroll
        for (int dh = 0; dh < 4; ++dh)
          Bv[dh] = *(const h8*)(VTp + (size_t)(wd0 + dh * 16 + c) * cM + kk * 32 + g * 8);
      } else {
#pragma unroll
        for (int dh = 0; dh < 4; ++dh) {
#pragma unroll
          for (int j = 0; j < 8; ++j)
            Bv[dh][j] = (_Float16)Vf[(size_t)(kk * 32 + g * 8 + j) * cD + wd0 + dh * 16 + c];
        }
      }
#pragma unroll
      for (int a = 0; a < 4; ++a)
#pragma unroll
        for (int dh = 0; dh < 4; ++dh)
          acc[a][dh] = __builtin_amdgcn_mfma_f32_16x16x32_f16(A[a], Bv[dh], acc[a][dh], 0, 0, 0);
    }

    // ---- normalize, dot (cross-wave), gate, update ----
    float dtp[4][4];
#pragma unroll
    for (int a = 0; a < 4; ++a)
#pragma unroll
      for (int r = 0; r < 4; ++r) {
        float dp = 0.f;
#pragma unroll
        for (int dh = 0; dh < 4; ++dh) {
          acc[a][dh][r] *= rsum[a][r];
          dp = fmaf(y[a][dh][r], acc[a][dh][r], dp);
        }
        dp += __shfl_xor(dp, 1, 64);
        dp += __shfl_xor(dp, 2, 64);
        dp += __shfl_xor(dp, 4, 64);
        dp += __shfl_xor(dp, 8, 64);
        dtp[a][r] = dp;
      }
    {
      int row = (c >> 2) * 16 + g * 4 + (c & 3);
      reddot[row * 4 + wid] = sel16(dtp, c);
    }
    __syncthreads(); // also protects stage reuse next step
#pragma unroll
    for (int a = 0; a < 4; ++a)
#pragma unroll
      for (int r = 0; r < 4; ++r) {
        f4 q = *(const f4*)&reddot[(a * 16 + g * 4 + r) * 4];
        float dot = (q[0] + q[1]) + (q[2] + q[3]);
        float x = fmaf(ga, dot, gb);
        float gate = 1.f / (1.f + exp2f(-LOG2E * x));
#pragma unroll
        for (int dh = 0; dh < 4; ++dh)
          y[a][dh][r] = fmaf(gate, acc[a][dh][r], y[a][dh][r]);
      }
  }

  if (PART) {
    // plain store of this block's y tile; tile_id == bid by construction
    float* pp = outOrPart + (size_t)bid * (64 * 256);
#pragma unroll
    for (int a = 0; a < 4; ++a)
#pragma unroll
      for (int r = 0; r < 4; ++r) {
        int row = a * 16 + g * 4 + r;
#pragma unroll
        for (int dh = 0; dh < 4; ++dh)
          pp[row * 256 + wd0 + dh * 16 + c] = y[a][dh][r];
      }
  } else {
    // out += y_k (out pre-initialized to -4*seed by k_init)
    float* op = outOrPart + (size_t)b * cN * cD;
#pragma unroll
    for (int a = 0; a < 4; ++a)
#pragma unroll
      for (int r = 0; r < 4; ++r) {
        float* rp = op + (size_t)(n0 + a * 16 + g * 4 + r) * cD + wd0 + c;
#pragma unroll
        for (int dh = 0; dh < 4; ++dh) atomicAdd(rp + dh * 16, y[a][dh][r]);
      }
  }
}

extern "C" void kernel_launch(void* const* d_in, const int* in_sizes, int n_in,
                              void* d_out, int out_size, void* d_ws, size_t ws_size,
                              hipStream_t stream) {
  const float* seed = (const float*)d_in[0];
  const float* emK = (const float*)d_in[1];
  const float* emV = (const float*)d_in[2];
  const float* emS = (const float*)d_in[3];
  const float* ga = (const float*)d_in[4];
  const float* gb = (const float*)d_in[5];
  const float* rt = (const float*)d_in[6];
  float* out = (float*)d_out;

  unsigned short* Kh = (unsigned short*)d_ws;
  bool pre = (d_ws != nullptr) && (ws_size >= KV_BYTES_F16);
  bool part = pre && (ws_size >= KV_BYTES_F16 + YPART_BYTES);
  unsigned short* VTh = pre ? (Kh + KV_ELEMS) : Kh;
  float* ypart = (float*)((char*)d_ws + KV_BYTES_F16);

  if (part) {
    k_prep<<<dim3(1536), dim3(256), 0, stream>>>((const f4*)emK, Kh, emV, VTh);
    ep_main<true, true><<<dim3(1024), dim3(256), 0, stream>>>(seed, emK, emV, emS, ga, gb,
                                                              rt, Kh, VTh, ypart);
    k_reduce<<<dim3(1024), dim3(256), 0, stream>>>((const f4*)seed, (const f4*)ypart,
                                                   (f4*)out);
  } else if (pre) {
    k_init<<<dim3(1024), dim3(256), 0, stream>>>((const f4*)seed, (f4*)out);
    k_prep<<<dim3(1536), dim3(256), 0, stream>>>((const f4*)emK, Kh, emV, VTh);
    ep_main<true, false><<<dim3(1024), dim3(256), 0, stream>>>(seed, emK, emV, emS, ga, gb,
                                                               rt, Kh, VTh, out);
  } else {
    k_init<<<dim3(1024), dim3(256), 0, stream>>>((const f4*)seed, (f4*)out);
    ep_main<false, false><<<dim3(1024), dim3(256), 0, stream>>>(seed, emK, emV, emS, ga, gb,
                                                                rt, Kh, VTh, out);
  }
}

// Round 6
// 390.985 us; speedup vs baseline: 1.1947x; 1.1947x over previous
//
#include <hip/hip_runtime.h>
#include <math.h>

typedef float    f4 __attribute__((ext_vector_type(4)));
typedef _Float16 h8 __attribute__((ext_vector_type(8)));
typedef _Float16 h4 __attribute__((ext_vector_type(4)));

static constexpr int cBS = 8, cB = 4, cM = 256, cD = 256, cN = 2048;
static constexpr size_t KV_ELEMS = (size_t)cBS * cB * cM * cD;      // 2,097,152 floats
static constexpr size_t KV_BYTES_F16 = 2 * KV_ELEMS * 2;            // Kh + VTh = 8 MB
static constexpr size_t YPART_ELEMS = (size_t)cBS * cB * cN * cD;   // 16,777,216 floats
static constexpr size_t YPART_BYTES = YPART_ELEMS * 4;              // 64 MB

// select v[c>>2][c&3] with compile-time indices only (avoid scratch)
__device__ __forceinline__ float sel16(const float v[4][4], int c) {
  float s = v[0][0];
#pragma unroll
  for (int a = 0; a < 4; ++a)
#pragma unroll
    for (int r = 0; r < 4; ++r) {
      int idx = a * 4 + r;
      if (idx) s = (c == idx) ? v[a][r] : s;
    }
  return s;
}

// out = -4 * seed  (atomic-fallback path only)
__global__ void k_init(const f4* __restrict__ seed, f4* __restrict__ out) {
  int i = blockIdx.x * 256 + threadIdx.x; // ×4 iters = 1,048,576 f4 = seed size
#pragma unroll
  for (int j = 0; j < 4; ++j) {
    int idx = i + j * 262144;
    f4 v = seed[idx];
    out[idx] = -4.0f * v;
  }
}

// out = ypart[k=0..3] summed - 4*seed   (ws path)
__global__ void k_reduce(const f4* __restrict__ seed, const f4* __restrict__ ypart,
                         f4* __restrict__ out) {
  int i = blockIdx.x * 256 + threadIdx.x;
#pragma unroll
  for (int j = 0; j < 4; ++j) {
    int idx = i + j * 262144;          // f4 index into out/seed
    int d4 = idx & 63;                 // d/4
    int n = (idx >> 6) & 2047;
    int b = idx >> 17;
    int nt = n >> 6, row = n & 63;
    size_t base = ((size_t)((b * 128 + nt) * 64 + row)) * 64 + d4; // k=0 tile
    f4 acc = ypart[base] + ypart[base + 131072] + ypart[base + 2 * 131072] +
             ypart[base + 3 * 131072];
    out[idx] = acc - 4.0f * seed[idx];
  }
}

// blocks [0,512): transpose V -> VT (f16, [bk][d][m]); blocks [512,1536): K -> f16
__global__ __launch_bounds__(256) void k_prep(const f4* __restrict__ K,
                                              unsigned short* __restrict__ Kh,
                                              const float* __restrict__ V,
                                              unsigned short* __restrict__ VT) {
  __shared__ float t[64][65];
  int bid = blockIdx.x;
  int tid = threadIdx.x;
  if (bid < 512) {
    int dt = bid & 3, mt = (bid >> 2) & 3, bkk = bid >> 4; // bkk 0..31
    const float* src = V + (size_t)bkk * 65536 + (size_t)(mt * 64) * 256 + dt * 64;
#pragma unroll
    for (int i = 0; i < 4; ++i) {
      int idx = tid + i * 256;
      int r = idx >> 4, cq = idx & 15;
      f4 v = *(const f4*)(src + (size_t)r * 256 + cq * 4);
      t[r][cq * 4 + 0] = v[0]; t[r][cq * 4 + 1] = v[1];
      t[r][cq * 4 + 2] = v[2]; t[r][cq * 4 + 3] = v[3];
    }
    __syncthreads();
    _Float16* dst = reinterpret_cast<_Float16*>(VT) + (size_t)bkk * 65536 +
                    (size_t)(dt * 64) * 256 + mt * 64;
#pragma unroll
    for (int i = 0; i < 4; ++i) {
      int idx = tid + i * 256;
      int d = idx >> 4, mq = idx & 15;
      h4 h;
      h[0] = (_Float16)t[mq * 4 + 0][d];
      h[1] = (_Float16)t[mq * 4 + 1][d];
      h[2] = (_Float16)t[mq * 4 + 2][d];
      h[3] = (_Float16)t[mq * 4 + 3][d];
      *(h4*)(dst + (size_t)d * 256 + mq * 4) = h;
    }
  } else {
    int i = (bid - 512) * 256 + tid; // ×2 iters = 524,288 f4 = K size
    _Float16* kp = reinterpret_cast<_Float16*>(Kh);
#pragma unroll
    for (int j = 0; j < 2; ++j) {
      int idx = i + j * 262144;
      f4 v = K[idx];
      h4 h;
      h[0] = (_Float16)v[0]; h[1] = (_Float16)v[1];
      h[2] = (_Float16)v[2]; h[3] = (_Float16)v[3];
      *(h4*)(kp + (size_t)idx * 4) = h;
    }
  }
}

// 8 waves/block, 32-wide m/d slices per wave: per-thread live state ~110 regs,
// fits the 128-VGPR cap the allocator insists on (r3/r4 both spilled ~450MB/disp
// at 4 waves × 64-wide slices with ~200 live).
template <bool PRE, bool PART>
__global__ __launch_bounds__(512, 2)
void ep_main(const float* __restrict__ seed, const float* __restrict__ emK,
             const float* __restrict__ emV, const float* __restrict__ emS,
             const float* __restrict__ galpha, const float* __restrict__ gbias,
             const float* __restrict__ rtau, const unsigned short* __restrict__ KhRaw,
             const unsigned short* __restrict__ VThRaw, float* __restrict__ outOrPart) {
  __shared__ _Float16 stage[64 * 256]; // 32KB, swizzled; reused y-stage then P
  __shared__ float redmax[512], redsum[512], reddot[512];

  const int tid = threadIdx.x, wid = tid >> 6, lane = tid & 63;
  const int g = lane >> 4, c = lane & 15;
  const int bid = blockIdx.x;
  const int nt = bid & 31, k = (bid >> 5) & 3, b = bid >> 7;
  const int n0 = nt * 64, wm0 = wid * 32, wd0 = wid * 32;

  const float LOG2E = 1.4426950408889634f;
  float rt = rtau[k];
  float tau = ((rt > 20.f) ? rt : log1pf(expf(rt))) + 0.1f;
  float scale2 = LOG2E / tau;
  float ga = galpha[k] * (1.0f / 256.0f);
  float gb = gbias[k];

  float msk[2];
#pragma unroll
  for (int mh = 0; mh < 2; ++mh) {
    float sv = emS[(b * cB + k) * cM + wm0 + mh * 16 + c];
    msk[mh] = (sv > 0.f) ? 0.f : -1e30f;
  }

  // y state: y[a][dh][r] = y[n0+a*16+g*4+r][wd0+dh*16+c]  (32 f32/thread)
  float y[4][2][4];
  {
    const float* s0 = seed + (size_t)b * cN * cD;
#pragma unroll
    for (int a = 0; a < 4; ++a)
#pragma unroll
      for (int r = 0; r < 4; ++r) {
        const float* rp = s0 + (size_t)(n0 + a * 16 + g * 4 + r) * cD + wd0 + c;
#pragma unroll
        for (int dh = 0; dh < 2; ++dh) y[a][dh][r] = rp[dh * 16];
      }
  }

  const size_t bk = (size_t)(b * cB + k);
  const _Float16* Kp = reinterpret_cast<const _Float16*>(KhRaw) + bk * cM * cD;
  const _Float16* VTp = reinterpret_cast<const _Float16*>(VThRaw) + bk * cD * cM;
  const float* Kf = emK + bk * cM * cD;
  const float* Vf = emV + bk * cM * cD;

  f4 acc[4][2];
  float rmax[4][4], rsum[4][4];

  for (int step = 0; step < 2; ++step) {
    // ---- stage y as f16 (swizzled) ----
#pragma unroll
    for (int a = 0; a < 4; ++a)
#pragma unroll
      for (int r = 0; r < 4; ++r) {
        int row = a * 16 + g * 4 + r;
        int sw = (row & 7) << 4;
#pragma unroll
        for (int dh = 0; dh < 2; ++dh) {
          int byte = ((row << 9) + ((wd0 + dh * 16 + c) << 1)) ^ sw;
          *(_Float16*)((char*)stage + byte) = (_Float16)y[a][dh][r];
        }
      }
    __syncthreads();

    // ---- S = y @ K^T (wave owns m-slice wm0..wm0+31) ----
#pragma unroll
    for (int a = 0; a < 4; ++a)
#pragma unroll
      for (int mh = 0; mh < 2; ++mh)
#pragma unroll
        for (int r = 0; r < 4; ++r) acc[a][mh][r] = 0.f;

    for (int kk = 0; kk < 8; ++kk) {
      h8 A[4], Bv[2];
#pragma unroll
      for (int a = 0; a < 4; ++a) {
        int row = a * 16 + c;
        int byte = ((row << 9) + (kk << 6) + (g << 4)) ^ ((row & 7) << 4);
        A[a] = *(const h8*)((const char*)stage + byte);
      }
      if (PRE) {
#pragma unroll
        for (int mh = 0; mh < 2; ++mh)
          Bv[mh] = *(const h8*)(Kp + (size_t)(wm0 + mh * 16 + c) * cD + kk * 32 + g * 8);
      } else {
#pragma unroll
        for (int mh = 0; mh < 2; ++mh) {
          const float* p = Kf + (size_t)(wm0 + mh * 16 + c) * cD + kk * 32 + g * 8;
#pragma unroll
          for (int j = 0; j < 8; ++j) Bv[mh][j] = (_Float16)p[j];
        }
      }
#pragma unroll
      for (int a = 0; a < 4; ++a)
#pragma unroll
        for (int mh = 0; mh < 2; ++mh)
          acc[a][mh] = __builtin_amdgcn_mfma_f32_16x16x32_f16(A[a], Bv[mh], acc[a][mh], 0, 0, 0);
    }

    // ---- scale + mask + wave row-max over its 32 cols ----
#pragma unroll
    for (int a = 0; a < 4; ++a)
#pragma unroll
      for (int r = 0; r < 4; ++r) {
#pragma unroll
        for (int mh = 0; mh < 2; ++mh)
          acc[a][mh][r] = fmaf(acc[a][mh][r], scale2, msk[mh]);
        float v = fmaxf(acc[a][0][r], acc[a][1][r]);
        v = fmaxf(v, __shfl_xor(v, 1, 64));
        v = fmaxf(v, __shfl_xor(v, 2, 64));
        v = fmaxf(v, __shfl_xor(v, 4, 64));
        v = fmaxf(v, __shfl_xor(v, 8, 64));
        rmax[a][r] = v;
      }
    {
      int row = (c >> 2) * 16 + g * 4 + (c & 3);
      redmax[row * 8 + wid] = sel16(rmax, c);
    }
    __syncthreads();
#pragma unroll
    for (int a = 0; a < 4; ++a)
#pragma unroll
      for (int r = 0; r < 4; ++r) {
        int row = a * 16 + g * 4 + r;
        f4 q0 = *(const f4*)&redmax[row * 8];
        f4 q1 = *(const f4*)&redmax[row * 8 + 4];
        rmax[a][r] = fmaxf(fmaxf(fmaxf(q0[0], q0[1]), fmaxf(q0[2], q0[3])),
                           fmaxf(fmaxf(q1[0], q1[1]), fmaxf(q1[2], q1[3])));
      }

    // ---- exp ----
#pragma unroll
    for (int a = 0; a < 4; ++a)
#pragma unroll
      for (int mh = 0; mh < 2; ++mh)
#pragma unroll
        for (int r = 0; r < 4; ++r)
          acc[a][mh][r] = exp2f(acc[a][mh][r] - rmax[a][r]);

    // ---- write P (f16) into stage (all y A-reads done before redmax barrier) ----
#pragma unroll
    for (int a = 0; a < 4; ++a)
#pragma unroll
      for (int r = 0; r < 4; ++r) {
        int row = a * 16 + g * 4 + r;
        int sw = (row & 7) << 4;
#pragma unroll
        for (int mh = 0; mh < 2; ++mh) {
          int byte = ((row << 9) + ((wm0 + mh * 16 + c) << 1)) ^ sw;
          *(_Float16*)((char*)stage + byte) = (_Float16)acc[a][mh][r];
        }
      }

    // ---- wave row-sum ----
#pragma unroll
    for (int a = 0; a < 4; ++a)
#pragma unroll
      for (int r = 0; r < 4; ++r) {
        float v = acc[a][0][r] + acc[a][1][r];
        v += __shfl_xor(v, 1, 64);
        v += __shfl_xor(v, 2, 64);
        v += __shfl_xor(v, 4, 64);
        v += __shfl_xor(v, 8, 64);
        rsum[a][r] = v;
      }
    {
      int row = (c >> 2) * 16 + g * 4 + (c & 3);
      redsum[row * 8 + wid] = sel16(rsum, c);
    }
    __syncthreads(); // also covers P-writes
#pragma unroll
    for (int a = 0; a < 4; ++a)
#pragma unroll
      for (int r = 0; r < 4; ++r) {
        int row = a * 16 + g * 4 + r;
        f4 q0 = *(const f4*)&redsum[row * 8];
        f4 q1 = *(const f4*)&redsum[row * 8 + 4];
        float s = ((q0[0] + q0[1]) + (q0[2] + q0[3])) +
                  ((q1[0] + q1[1]) + (q1[2] + q1[3]));
        rsum[a][r] = (s > 0.f && rmax[a][r] > -1e29f) ? (1.f / s) : 0.f;
      }

    // ---- delta = P @ V (wave owns d-slice wd0..wd0+31) ----
#pragma unroll
    for (int a = 0; a < 4; ++a)
#pragma unroll
      for (int dh = 0; dh < 2; ++dh)
#pragma unroll
        for (int r = 0; r < 4; ++r) acc[a][dh][r] = 0.f;

    for (int kk = 0; kk < 8; ++kk) {
      h8 A[4], Bv[2];
#pragma unroll
      for (int a = 0; a < 4; ++a) {
        int row = a * 16 + c;
        int byte = ((row << 9) + (kk << 6) + (g << 4)) ^ ((row & 7) << 4);
        A[a] = *(const h8*)((const char*)stage + byte);
      }
      if (PRE) {
#pragma unroll
        for (int dh = 0; dh < 2; ++dh)
          Bv[dh] = *(const h8*)(VTp + (size_t)(wd0 + dh * 16 + c) * cM + kk * 32 + g * 8);
      } else {
#pragma unroll
        for (int dh = 0; dh < 2; ++dh) {
#pragma unroll
          for (int j = 0; j < 8; ++j)
            Bv[dh][j] = (_Float16)Vf[(size_t)(kk * 32 + g * 8 + j) * cD + wd0 + dh * 16 + c];
        }
      }
#pragma unroll
      for (int a = 0; a < 4; ++a)
#pragma unroll
        for (int dh = 0; dh < 2; ++dh)
          acc[a][dh] = __builtin_amdgcn_mfma_f32_16x16x32_f16(A[a], Bv[dh], acc[a][dh], 0, 0, 0);
    }

    // ---- normalize, dot (cross-wave), gate, update ----
    float dtp[4][4];
#pragma unroll
    for (int a = 0; a < 4; ++a)
#pragma unroll
      for (int r = 0; r < 4; ++r) {
        float dp = 0.f;
#pragma unroll
        for (int dh = 0; dh < 2; ++dh) {
          acc[a][dh][r] *= rsum[a][r];
          dp = fmaf(y[a][dh][r], acc[a][dh][r], dp);
        }
        dp += __shfl_xor(dp, 1, 64);
        dp += __shfl_xor(dp, 2, 64);
        dp += __shfl_xor(dp, 4, 64);
        dp += __shfl_xor(dp, 8, 64);
        dtp[a][r] = dp;
      }
    {
      int row = (c >> 2) * 16 + g * 4 + (c & 3);
      reddot[row * 8 + wid] = sel16(dtp, c);
    }
    __syncthreads(); // also protects stage reuse next step
#pragma unroll
    for (int a = 0; a < 4; ++a)
#pragma unroll
      for (int r = 0; r < 4; ++r) {
        int row = a * 16 + g * 4 + r;
        f4 q0 = *(const f4*)&reddot[row * 8];
        f4 q1 = *(const f4*)&reddot[row * 8 + 4];
        float dot = ((q0[0] + q0[1]) + (q0[2] + q0[3])) +
                    ((q1[0] + q1[1]) + (q1[2] + q1[3]));
        float x = fmaf(ga, dot, gb);
        float gate = 1.f / (1.f + exp2f(-LOG2E * x));
#pragma unroll
        for (int dh = 0; dh < 2; ++dh)
          y[a][dh][r] = fmaf(gate, acc[a][dh][r], y[a][dh][r]);
      }
  }

  if (PART) {
    // plain store of this block's y tile; tile_id == bid by construction
    float* pp = outOrPart + (size_t)bid * (64 * 256);
#pragma unroll
    for (int a = 0; a < 4; ++a)
#pragma unroll
      for (int r = 0; r < 4; ++r) {
        int row = a * 16 + g * 4 + r;
#pragma unroll
        for (int dh = 0; dh < 2; ++dh)
          pp[row * 256 + wd0 + dh * 16 + c] = y[a][dh][r];
      }
  } else {
    // out += y_k (out pre-initialized to -4*seed by k_init)
    float* op = outOrPart + (size_t)b * cN * cD;
#pragma unroll
    for (int a = 0; a < 4; ++a)
#pragma unroll
      for (int r = 0; r < 4; ++r) {
        float* rp = op + (size_t)(n0 + a * 16 + g * 4 + r) * cD + wd0 + c;
#pragma unroll
        for (int dh = 0; dh < 2; ++dh) atomicAdd(rp + dh * 16, y[a][dh][r]);
      }
  }
}

extern "C" void kernel_launch(void* const* d_in, const int* in_sizes, int n_in,
                              void* d_out, int out_size, void* d_ws, size_t ws_size,
                              hipStream_t stream) {
  const float* seed = (const float*)d_in[0];
  const float* emK = (const float*)d_in[1];
  const float* emV = (const float*)d_in[2];
  const float* emS = (const float*)d_in[3];
  const float* ga = (const float*)d_in[4];
  const float* gb = (const float*)d_in[5];
  const float* rt = (const float*)d_in[6];
  float* out = (float*)d_out;

  unsigned short* Kh = (unsigned short*)d_ws;
  bool pre = (d_ws != nullptr) && (ws_size >= KV_BYTES_F16);
  bool part = pre && (ws_size >= KV_BYTES_F16 + YPART_BYTES);
  unsigned short* VTh = pre ? (Kh + KV_ELEMS) : Kh;
  float* ypart = (float*)((char*)d_ws + KV_BYTES_F16);

  if (part) {
    k_prep<<<dim3(1536), dim3(256), 0, stream>>>((const f4*)emK, Kh, emV, VTh);
    ep_main<true, true><<<dim3(1024), dim3(512), 0, stream>>>(seed, emK, emV, emS, ga, gb,
                                                              rt, Kh, VTh, ypart);
    k_reduce<<<dim3(1024), dim3(256), 0, stream>>>((const f4*)seed, (const f4*)ypart,
                                                   (f4*)out);
  } else if (pre) {
    k_init<<<dim3(1024), dim3(256), 0, stream>>>((const f4*)seed, (f4*)out);
    k_prep<<<dim3(1536), dim3(256), 0, stream>>>((const f4*)emK, Kh, emV, VTh);
    ep_main<true, false><<<dim3(1024), dim3(512), 0, stream>>>(seed, emK, emV, emS, ga, gb,
                                                               rt, Kh, VTh, out);
  } else {
    k_init<<<dim3(1024), dim3(256), 0, stream>>>((const f4*)seed, (f4*)out);
    ep_main<false, false><<<dim3(1024), dim3(512), 0, stream>>>(seed, emK, emV, emS, ga, gb,
                                                                rt, Kh, VTh, out);
  }
}

// Round 7
// 299.020 us; speedup vs baseline: 1.5621x; 1.3076x over previous
//
#include <hip/hip_runtime.h>
#include <math.h>

typedef float    f4 __attribute__((ext_vector_type(4)));
typedef _Float16 h8 __attribute__((ext_vector_type(8)));
typedef _Float16 h4 __attribute__((ext_vector_type(4)));

static constexpr int cBS = 8, cB = 4, cM = 256, cD = 256, cN = 2048;
static constexpr size_t KV_ELEMS = (size_t)cBS * cB * cM * cD;      // 2,097,152 floats
static constexpr size_t KV_BYTES_F16 = 2 * KV_ELEMS * 2;            // Kh + VTh = 8 MB
static constexpr size_t YPART_ELEMS = (size_t)cBS * cB * cN * cD;   // 16,777,216 floats
static constexpr size_t YPART_BYTES = YPART_ELEMS * 4;              // 64 MB

// select v[c>>2][c&3] (c in 0..7) with compile-time indices only
__device__ __forceinline__ float sel8(const float v[2][4], int c) {
  float s = v[0][0];
#pragma unroll
  for (int a = 0; a < 2; ++a)
#pragma unroll
    for (int r = 0; r < 4; ++r) {
      int idx = a * 4 + r;
      if (idx) s = (c == idx) ? v[a][r] : s;
    }
  return s;
}

// out = -4 * seed  (atomic-fallback path only)
__global__ void k_init(const f4* __restrict__ seed, f4* __restrict__ out) {
  int i = blockIdx.x * 256 + threadIdx.x; // ×4 iters = 1,048,576 f4 = seed size
#pragma unroll
  for (int j = 0; j < 4; ++j) {
    int idx = i + j * 262144;
    f4 v = seed[idx];
    out[idx] = -4.0f * v;
  }
}

// out = ypart[k=0..3] summed - 4*seed   (ws path)
// ypart layout: [bid][32][256] with bid = b*256 + k*64 + nt  (32-row tiles)
__global__ void k_reduce(const f4* __restrict__ seed, const f4* __restrict__ ypart,
                         f4* __restrict__ out) {
  int i = blockIdx.x * 256 + threadIdx.x;
#pragma unroll
  for (int j = 0; j < 4; ++j) {
    int idx = i + j * 262144;          // f4 index into out/seed
    int d4 = idx & 63;                 // d/4
    int n = (idx >> 6) & 2047;
    int b = idx >> 17;
    int nt = n >> 5, row = n & 31;
    size_t base = ((size_t)((b * 256 + nt) * 32 + row)) * 64 + d4; // k=0 tile
    f4 acc = ypart[base] + ypart[base + 131072] + ypart[base + 2 * 131072] +
             ypart[base + 3 * 131072];
    out[idx] = acc - 4.0f * seed[idx];
  }
}

// blocks [0,512): transpose V -> VT (f16, [bk][d][m]); blocks [512,1536): K -> f16
__global__ __launch_bounds__(256) void k_prep(const f4* __restrict__ K,
                                              unsigned short* __restrict__ Kh,
                                              const float* __restrict__ V,
                                              unsigned short* __restrict__ VT) {
  __shared__ float t[64][65];
  int bid = blockIdx.x;
  int tid = threadIdx.x;
  if (bid < 512) {
    int dt = bid & 3, mt = (bid >> 2) & 3, bkk = bid >> 4; // bkk 0..31
    const float* src = V + (size_t)bkk * 65536 + (size_t)(mt * 64) * 256 + dt * 64;
#pragma unroll
    for (int i = 0; i < 4; ++i) {
      int idx = tid + i * 256;
      int r = idx >> 4, cq = idx & 15;
      f4 v = *(const f4*)(src + (size_t)r * 256 + cq * 4);
      t[r][cq * 4 + 0] = v[0]; t[r][cq * 4 + 1] = v[1];
      t[r][cq * 4 + 2] = v[2]; t[r][cq * 4 + 3] = v[3];
    }
    __syncthreads();
    _Float16* dst = reinterpret_cast<_Float16*>(VT) + (size_t)bkk * 65536 +
                    (size_t)(dt * 64) * 256 + mt * 64;
#pragma unroll
    for (int i = 0; i < 4; ++i) {
      int idx = tid + i * 256;
      int d = idx >> 4, mq = idx & 15;
      h4 h;
      h[0] = (_Float16)t[mq * 4 + 0][d];
      h[1] = (_Float16)t[mq * 4 + 1][d];
      h[2] = (_Float16)t[mq * 4 + 2][d];
      h[3] = (_Float16)t[mq * 4 + 3][d];
      *(h4*)(dst + (size_t)d * 256 + mq * 4) = h;
    }
  } else {
    int i = (bid - 512) * 256 + tid; // ×2 iters = 524,288 f4 = K size
    _Float16* kp = reinterpret_cast<_Float16*>(Kh);
#pragma unroll
    for (int j = 0; j < 2; ++j) {
      int idx = i + j * 262144;
      f4 v = K[idx];
      h4 h;
      h[0] = (_Float16)v[0]; h[1] = (_Float16)v[1];
      h[2] = (_Float16)v[2]; h[3] = (_Float16)v[3];
      *(h4*)(kp + (size_t)idx * 4) = h;
    }
  }
}

// 32-row tiles × 2048 blocks × 8 waves (32-wide slices): per-thread base liveness
// ~55 regs, leaving ~70 of slack for the scheduler's unroll pipelining.
// r3/r6 lesson: full-unroll software pipelining adds 2-3× the transient set on
// top of base liveness; at 64-row tiles that overflowed 128 and the hot-loop
// spill slots produced ~0.8 GB/dispatch of scratch traffic.
template <bool PRE, bool PART>
__global__ __launch_bounds__(512, 2)
void ep_main(const float* __restrict__ seed, const float* __restrict__ emK,
             const float* __restrict__ emV, const float* __restrict__ emS,
             const float* __restrict__ galpha, const float* __restrict__ gbias,
             const float* __restrict__ rtau, const unsigned short* __restrict__ KhRaw,
             const unsigned short* __restrict__ VThRaw, float* __restrict__ outOrPart) {
  __shared__ _Float16 stage[32 * 256]; // 16KB, swizzled; reused y-stage then P
  __shared__ float redmax[256], redsum[256], reddot[256];

  const int tid = threadIdx.x, wid = tid >> 6, lane = tid & 63;
  const int g = lane >> 4, c = lane & 15;
  const int bid = blockIdx.x;
  const int nt = bid & 63, k = (bid >> 6) & 3, b = bid >> 8;
  const int n0 = nt * 32, wm0 = wid * 32, wd0 = wid * 32;

  const float LOG2E = 1.4426950408889634f;
  float rt = rtau[k];
  float tau = ((rt > 20.f) ? rt : log1pf(expf(rt))) + 0.1f;
  float scale2 = LOG2E / tau;
  float ga = galpha[k] * (1.0f / 256.0f);
  float gb = gbias[k];

  float msk[2];
#pragma unroll
  for (int mh = 0; mh < 2; ++mh) {
    float sv = emS[(b * cB + k) * cM + wm0 + mh * 16 + c];
    msk[mh] = (sv > 0.f) ? 0.f : -1e30f;
  }

  // y state: y[a][dh][r] = y[n0+a*16+g*4+r][wd0+dh*16+c]  (16 f32/thread)
  float y[2][2][4];
  {
    const float* s0 = seed + (size_t)b * cN * cD;
#pragma unroll
    for (int a = 0; a < 2; ++a)
#pragma unroll
      for (int r = 0; r < 4; ++r) {
        const float* rp = s0 + (size_t)(n0 + a * 16 + g * 4 + r) * cD + wd0 + c;
#pragma unroll
        for (int dh = 0; dh < 2; ++dh) y[a][dh][r] = rp[dh * 16];
      }
  }

  const size_t bk = (size_t)(b * cB + k);
  const _Float16* Kp = reinterpret_cast<const _Float16*>(KhRaw) + bk * cM * cD;
  const _Float16* VTp = reinterpret_cast<const _Float16*>(VThRaw) + bk * cD * cM;
  const float* Kf = emK + bk * cM * cD;
  const float* Vf = emV + bk * cM * cD;

  f4 acc[2][2];
  float rmax[2][4], rsum[2][4];

  for (int step = 0; step < 2; ++step) {
    // ---- stage y as f16 (swizzled) ----
#pragma unroll
    for (int a = 0; a < 2; ++a)
#pragma unroll
      for (int r = 0; r < 4; ++r) {
        int row = a * 16 + g * 4 + r;
        int sw = (row & 7) << 4;
#pragma unroll
        for (int dh = 0; dh < 2; ++dh) {
          int byte = ((row << 9) + ((wd0 + dh * 16 + c) << 1)) ^ sw;
          *(_Float16*)((char*)stage + byte) = (_Float16)y[a][dh][r];
        }
      }
    __syncthreads();

    // ---- S = y @ K^T (wave owns m-slice wm0..wm0+31) ----
#pragma unroll
    for (int a = 0; a < 2; ++a)
#pragma unroll
      for (int mh = 0; mh < 2; ++mh)
#pragma unroll
        for (int r = 0; r < 4; ++r) acc[a][mh][r] = 0.f;

    for (int kk = 0; kk < 8; ++kk) {
      h8 A[2], Bv[2];
#pragma unroll
      for (int a = 0; a < 2; ++a) {
        int row = a * 16 + c;
        int byte = ((row << 9) + (kk << 6) + (g << 4)) ^ ((row & 7) << 4);
        A[a] = *(const h8*)((const char*)stage + byte);
      }
      if (PRE) {
#pragma unroll
        for (int mh = 0; mh < 2; ++mh)
          Bv[mh] = *(const h8*)(Kp + (size_t)(wm0 + mh * 16 + c) * cD + kk * 32 + g * 8);
      } else {
#pragma unroll
        for (int mh = 0; mh < 2; ++mh) {
          const float* p = Kf + (size_t)(wm0 + mh * 16 + c) * cD + kk * 32 + g * 8;
#pragma unroll
          for (int j = 0; j < 8; ++j) Bv[mh][j] = (_Float16)p[j];
        }
      }
#pragma unroll
      for (int a = 0; a < 2; ++a)
#pragma unroll
        for (int mh = 0; mh < 2; ++mh)
          acc[a][mh] = __builtin_amdgcn_mfma_f32_16x16x32_f16(A[a], Bv[mh], acc[a][mh], 0, 0, 0);
    }

    // ---- scale + mask + wave row-max over its 32 cols ----
#pragma unroll
    for (int a = 0; a < 2; ++a)
#pragma unroll
      for (int r = 0; r < 4; ++r) {
#pragma unroll
        for (int mh = 0; mh < 2; ++mh)
          acc[a][mh][r] = fmaf(acc[a][mh][r], scale2, msk[mh]);
        float v = fmaxf(acc[a][0][r], acc[a][1][r]);
        v = fmaxf(v, __shfl_xor(v, 1, 64));
        v = fmaxf(v, __shfl_xor(v, 2, 64));
        v = fmaxf(v, __shfl_xor(v, 4, 64));
        v = fmaxf(v, __shfl_xor(v, 8, 64));
        rmax[a][r] = v;
      }
    if (c < 8) {
      int row = (c >> 2) * 16 + g * 4 + (c & 3);
      redmax[row * 8 + wid] = sel8(rmax, c);
    }
    __syncthreads();
#pragma unroll
    for (int a = 0; a < 2; ++a)
#pragma unroll
      for (int r = 0; r < 4; ++r) {
        int row = a * 16 + g * 4 + r;
        f4 q0 = *(const f4*)&redmax[row * 8];
        f4 q1 = *(const f4*)&redmax[row * 8 + 4];
        rmax[a][r] = fmaxf(fmaxf(fmaxf(q0[0], q0[1]), fmaxf(q0[2], q0[3])),
                           fmaxf(fmaxf(q1[0], q1[1]), fmaxf(q1[2], q1[3])));
      }

    // ---- exp ----
#pragma unroll
    for (int a = 0; a < 2; ++a)
#pragma unroll
      for (int mh = 0; mh < 2; ++mh)
#pragma unroll
        for (int r = 0; r < 4; ++r)
          acc[a][mh][r] = exp2f(acc[a][mh][r] - rmax[a][r]);

    // ---- write P (f16) into stage (all y A-reads done before redmax barrier) ----
#pragma unroll
    for (int a = 0; a < 2; ++a)
#pragma unroll
      for (int r = 0; r < 4; ++r) {
        int row = a * 16 + g * 4 + r;
        int sw = (row & 7) << 4;
#pragma unroll
        for (int mh = 0; mh < 2; ++mh) {
          int byte = ((row << 9) + ((wm0 + mh * 16 + c) << 1)) ^ sw;
          *(_Float16*)((char*)stage + byte) = (_Float16)acc[a][mh][r];
        }
      }

    // ---- wave row-sum ----
#pragma unroll
    for (int a = 0; a < 2; ++a)
#pragma unroll
      for (int r = 0; r < 4; ++r) {
        float v = acc[a][0][r] + acc[a][1][r];
        v += __shfl_xor(v, 1, 64);
        v += __shfl_xor(v, 2, 64);
        v += __shfl_xor(v, 4, 64);
        v += __shfl_xor(v, 8, 64);
        rsum[a][r] = v;
      }
    if (c < 8) {
      int row = (c >> 2) * 16 + g * 4 + (c & 3);
      redsum[row * 8 + wid] = sel8(rsum, c);
    }
    __syncthreads(); // also covers P-writes
#pragma unroll
    for (int a = 0; a < 2; ++a)
#pragma unroll
      for (int r = 0; r < 4; ++r) {
        int row = a * 16 + g * 4 + r;
        f4 q0 = *(const f4*)&redsum[row * 8];
        f4 q1 = *(const f4*)&redsum[row * 8 + 4];
        float s = ((q0[0] + q0[1]) + (q0[2] + q0[3])) +
                  ((q1[0] + q1[1]) + (q1[2] + q1[3]));
        rsum[a][r] = (s > 0.f && rmax[a][r] > -1e29f) ? (1.f / s) : 0.f;
      }

    // ---- delta = P @ V (wave owns d-slice wd0..wd0+31) ----
#pragma unroll
    for (int a = 0; a < 2; ++a)
#pragma unroll
      for (int dh = 0; dh < 2; ++dh)
#pragma unroll
        for (int r = 0; r < 4; ++r) acc[a][dh][r] = 0.f;

    for (int kk = 0; kk < 8; ++kk) {
      h8 A[2], Bv[2];
#pragma unroll
      for (int a = 0; a < 2; ++a) {
        int row = a * 16 + c;
        int byte = ((row << 9) + (kk << 6) + (g << 4)) ^ ((row & 7) << 4);
        A[a] = *(const h8*)((const char*)stage + byte);
      }
      if (PRE) {
#pragma unroll
        for (int dh = 0; dh < 2; ++dh)
          Bv[dh] = *(const h8*)(VTp + (size_t)(wd0 + dh * 16 + c) * cM + kk * 32 + g * 8);
      } else {
#pragma unroll
        for (int dh = 0; dh < 2; ++dh) {
#pragma unroll
          for (int j = 0; j < 8; ++j)
            Bv[dh][j] = (_Float16)Vf[(size_t)(kk * 32 + g * 8 + j) * cD + wd0 + dh * 16 + c];
        }
      }
#pragma unroll
      for (int a = 0; a < 2; ++a)
#pragma unroll
        for (int dh = 0; dh < 2; ++dh)
          acc[a][dh] = __builtin_amdgcn_mfma_f32_16x16x32_f16(A[a], Bv[dh], acc[a][dh], 0, 0, 0);
    }

    // ---- normalize, dot (cross-wave), gate, update ----
    float dtp[2][4];
#pragma unroll
    for (int a = 0; a < 2; ++a)
#pragma unroll
      for (int r = 0; r < 4; ++r) {
        float dp = 0.f;
#pragma unroll
        for (int dh = 0; dh < 2; ++dh) {
          acc[a][dh][r] *= rsum[a][r];
          dp = fmaf(y[a][dh][r], acc[a][dh][r], dp);
        }
        dp += __shfl_xor(dp, 1, 64);
        dp += __shfl_xor(dp, 2, 64);
        dp += __shfl_xor(dp, 4, 64);
        dp += __shfl_xor(dp, 8, 64);
        dtp[a][r] = dp;
      }
    if (c < 8) {
      int row = (c >> 2) * 16 + g * 4 + (c & 3);
      reddot[row * 8 + wid] = sel8(dtp, c);
    }
    __syncthreads(); // also protects stage reuse next step
#pragma unroll
    for (int a = 0; a < 2; ++a)
#pragma unroll
      for (int r = 0; r < 4; ++r) {
        int row = a * 16 + g * 4 + r;
        f4 q0 = *(const f4*)&reddot[row * 8];
        f4 q1 = *(const f4*)&reddot[row * 8 + 4];
        float dot = ((q0[0] + q0[1]) + (q0[2] + q0[3])) +
                    ((q1[0] + q1[1]) + (q1[2] + q1[3]));
        float x = fmaf(ga, dot, gb);
        float gate = 1.f / (1.f + exp2f(-LOG2E * x));
#pragma unroll
        for (int dh = 0; dh < 2; ++dh)
          y[a][dh][r] = fmaf(gate, acc[a][dh][r], y[a][dh][r]);
      }
  }

  if (PART) {
    // plain store of this block's y tile; tile_id == bid by construction
    float* pp = outOrPart + (size_t)bid * (32 * 256);
#pragma unroll
    for (int a = 0; a < 2; ++a)
#pragma unroll
      for (int r = 0; r < 4; ++r) {
        int row = a * 16 + g * 4 + r;
#pragma unroll
        for (int dh = 0; dh < 2; ++dh)
          pp[row * 256 + wd0 + dh * 16 + c] = y[a][dh][r];
      }
  } else {
    // out += y_k (out pre-initialized to -4*seed by k_init)
    float* op = outOrPart + (size_t)b * cN * cD;
#pragma unroll
    for (int a = 0; a < 2; ++a)
#pragma unroll
      for (int r = 0; r < 4; ++r) {
        float* rp = op + (size_t)(n0 + a * 16 + g * 4 + r) * cD + wd0 + c;
#pragma unroll
        for (int dh = 0; dh < 2; ++dh) atomicAdd(rp + dh * 16, y[a][dh][r]);
      }
  }
}

extern "C" void kernel_launch(void* const* d_in, const int* in_sizes, int n_in,
                              void* d_out, int out_size, void* d_ws, size_t ws_size,
                              hipStream_t stream) {
  const float* seed = (const float*)d_in[0];
  const float* emK = (const float*)d_in[1];
  const float* emV = (const float*)d_in[2];
  const float* emS = (const float*)d_in[3];
  const float* ga = (const float*)d_in[4];
  const float* gb = (const float*)d_in[5];
  const float* rt = (const float*)d_in[6];
  float* out = (float*)d_out;

  unsigned short* Kh = (unsigned short*)d_ws;
  bool pre = (d_ws != nullptr) && (ws_size >= KV_BYTES_F16);
  bool part = pre && (ws_size >= KV_BYTES_F16 + YPART_BYTES);
  unsigned short* VTh = pre ? (Kh + KV_ELEMS) : Kh;
  float* ypart = (float*)((char*)d_ws + KV_BYTES_F16);

  if (part) {
    k_prep<<<dim3(1536), dim3(256), 0, stream>>>((const f4*)emK, Kh, emV, VTh);
    ep_main<true, true><<<dim3(2048), dim3(512), 0, stream>>>(seed, emK, emV, emS, ga, gb,
                                                              rt, Kh, VTh, ypart);
    k_reduce<<<dim3(1024), dim3(256), 0, stream>>>((const f4*)seed, (const f4*)ypart,
                                                   (f4*)out);
  } else if (pre) {
    k_init<<<dim3(1024), dim3(256), 0, stream>>>((const f4*)seed, (f4*)out);
    k_prep<<<dim3(1536), dim3(256), 0, stream>>>((const f4*)emK, Kh, emV, VTh);
    ep_main<true, false><<<dim3(2048), dim3(512), 0, stream>>>(seed, emK, emV, emS, ga, gb,
                                                               rt, Kh, VTh, out);
  } else {
    k_init<<<dim3(1024), dim3(256), 0, stream>>>((const f4*)seed, (f4*)out);
    ep_main<false, false><<<dim3(2048), dim3(512), 0, stream>>>(seed, emK, emV, emS, ga, gb,
                                                                rt, Kh, VTh, out);
  }
}